// Round 1
// baseline (306.699 us; speedup 1.0000x reference)
//
#include <hip/hip_runtime.h>

// Problem constants (from reference): N=30, K=100, ALPHA=0.5, B=1048576
#define NROWS   1048576
#define NPAIRS  28        // N-2 pairs (d1,d2)
#define NDP     56        // 2*(N-2) floats per delta_pred row
#define NS      31        // N+1 floats per S row
#define NBLOCKS 2048
#define NTHREADS 256

__global__ __launch_bounds__(NTHREADS) void loss_partial_kernel(
    const float* __restrict__ dp,   // [B, 56]
    const float* __restrict__ bx,   // [B, 2]
    const float* __restrict__ S1,   // [B, 31]
    const float* __restrict__ S2,   // [B, 31]
    const float* __restrict__ wp,   // scalar
    double* __restrict__ partial)   // [NBLOCKS]
{
    const int tid    = blockIdx.x * blockDim.x + threadIdx.x;
    const int stride = gridDim.x * blockDim.x;
    const float w = *wp;

    double acc = 0.0;
    for (int r = tid; r < NROWS; r += stride) {
        const float* s1 = S1 + (size_t)r * NS;
        const float* s2 = S2 + (size_t)r * NS;

        // Load S rows into registers (fully unrolled -> static indexing).
        float s1v[NS];
        float s2v[NS - 1];             // S2[:,30] is never used
        #pragma unroll
        for (int i = 0; i < NS; ++i)      s1v[i] = s1[i];
        #pragma unroll
        for (int i = 0; i < NS - 1; ++i)  s2v[i] = s2[i];

        const float2 b = *reinterpret_cast<const float2*>(bx + (size_t)r * 2);
        float sum = b.x * (s1v[1] - s1v[0]) + b.y * (s2v[1] - s2v[0]);

        // delta_pred row: 14 aligned float4 (r*224B, 16B-aligned).
        const float4* dpr = reinterpret_cast<const float4*>(dp + (size_t)r * NDP);
        #pragma unroll
        for (int q = 0; q < 14; ++q) {
            const float4 v = dpr[q];
            const int i = 2 * q;      // pair index
            // dp[2i]=d1[i], dp[2i+1]=d2[i]; dS1[i] = S1[i+2]-S1[i+1]
            sum += v.x * (s1v[i + 2] - s1v[i + 1]) + v.y * (s2v[i + 2] - s2v[i + 1]);
            sum += v.z * (s1v[i + 3] - s1v[i + 2]) + v.w * (s2v[i + 3] - s2v[i + 2]);
        }

        const float liab = fmaxf(s1v[NS - 1] - 100.0f, 0.0f);
        const float loss = w + fmaxf(liab - sum - w, 0.0f) * 2.0f;  // /(1-0.5)
        acc += (double)loss;
    }

    // Deterministic block reduction (double).
    __shared__ double sm[NTHREADS];
    sm[threadIdx.x] = acc;
    __syncthreads();
    #pragma unroll
    for (int s = NTHREADS / 2; s > 0; s >>= 1) {
        if (threadIdx.x < s) sm[threadIdx.x] += sm[threadIdx.x + s];
        __syncthreads();
    }
    if (threadIdx.x == 0) partial[blockIdx.x] = sm[0];
}

__global__ __launch_bounds__(NTHREADS) void loss_final_kernel(
    const double* __restrict__ partial, float* __restrict__ out)
{
    double acc = 0.0;
    for (int i = threadIdx.x; i < NBLOCKS; i += NTHREADS) acc += partial[i];
    __shared__ double sm[NTHREADS];
    sm[threadIdx.x] = acc;
    __syncthreads();
    #pragma unroll
    for (int s = NTHREADS / 2; s > 0; s >>= 1) {
        if (threadIdx.x < s) sm[threadIdx.x] += sm[threadIdx.x + s];
        __syncthreads();
    }
    if (threadIdx.x == 0) out[0] = (float)(sm[0] / (double)NROWS);
}

extern "C" void kernel_launch(void* const* d_in, const int* in_sizes, int n_in,
                              void* d_out, int out_size, void* d_ws, size_t ws_size,
                              hipStream_t stream)
{
    const float* dp = (const float*)d_in[0];   // delta_pred [B,56]
    const float* bx = (const float*)d_in[1];   // batch_x    [B,2]
    const float* S1 = (const float*)d_in[2];   // S1         [B,31]
    const float* S2 = (const float*)d_in[3];   // S2         [B,31]
    const float* w  = (const float*)d_in[4];   // scalar

    double* partial = (double*)d_ws;           // NBLOCKS doubles (16 KiB)
    float* out = (float*)d_out;

    loss_partial_kernel<<<NBLOCKS, NTHREADS, 0, stream>>>(dp, bx, S1, S2, w, partial);
    loss_final_kernel<<<1, NTHREADS, 0, stream>>>(partial, out);
}

// Round 2
// 96.317 us; speedup vs baseline: 3.1843x; 3.1843x over previous
//
#include <hip/hip_runtime.h>

// Problem: N=30, K=100, ALPHA=0.5, B=1048576
#define NROWS   1048576
#define TILE    64                        // rows per tile
#define NBLOCKS 2048
#define NTHREADS 256
#define TILES_TOTAL (NROWS / TILE)        // 16384
#define TILES_PER_BLOCK (TILES_TOTAL / NBLOCKS)  // 8

// Per-tile byte sizes (global, contiguous)
#define DP_TILE_B (TILE * 224)            // 14336 = 14 x 1KB chunks
#define S_TILE_B  (TILE * 124)            // 7936  = 7 x 1KB + 768B tail
#define BX_TILE_B (TILE * 8)              // 512B (reg-staged)

// LDS layout (bytes). S regions padded to 8KB.
#define LDS_DP 0
#define LDS_S1 14336
#define LDS_S2 (14336 + 8192)             // 22528
#define LDS_BX (14336 + 8192 + 8192)      // 30720
#define LDS_TOTAL (30720 + 512)           // 31232

// Async global->LDS: writes wave-uniform LDS base + lane*16, global addr per-lane.
#define GLDS16(g, l) __builtin_amdgcn_global_load_lds(                         \
    (const __attribute__((address_space(1))) void*)(g),                        \
    (__attribute__((address_space(3))) void*)(l), 16, 0, 0)

__global__ __launch_bounds__(NTHREADS) void loss_staged_kernel(
    const float* __restrict__ dp,   // [B, 56]
    const float* __restrict__ bx,   // [B, 2]
    const float* __restrict__ S1,   // [B, 31]
    const float* __restrict__ S2,   // [B, 31]
    const float* __restrict__ wp,   // scalar
    double* __restrict__ partial)   // [NBLOCKS]
{
    __shared__ __align__(16) unsigned char lds[LDS_TOTAL];
    __shared__ double sm[NTHREADS];

    const int tid  = threadIdx.x;
    const int lane = tid & 63;
    const int wv   = tid >> 6;
    const float w  = *wp;

    double acc = 0.0;
    const long tile0 = (long)blockIdx.x * TILES_PER_BLOCK;

    for (int tt = 0; tt < TILES_PER_BLOCK; ++tt) {
        const long tile = tile0 + tt;
        const char* dpg = (const char*)dp + tile * (long)DP_TILE_B;
        const char* s1g = (const char*)S1 + tile * (long)S_TILE_B;
        const char* s2g = (const char*)S2 + tile * (long)S_TILE_B;
        const char* bxg = (const char*)bx + tile * (long)BX_TILE_B;

        // ---- stage: dense 1KB-per-wave-instruction async DMA ----
        for (int c = wv; c < 14; c += 4)
            GLDS16(dpg + c * 1024 + lane * 16, lds + LDS_DP + c * 1024);
        for (int c = wv; c < 7; c += 4)
            GLDS16(s1g + c * 1024 + lane * 16, lds + LDS_S1 + c * 1024);
        for (int c = wv; c < 7; c += 4)
            GLDS16(s2g + c * 1024 + lane * 16, lds + LDS_S2 + c * 1024);
        // tails: 768B of each S tile + 512B bx, reg-staged (semantics-safe)
        if (tid < 48) {
            float4 v = *reinterpret_cast<const float4*>(s1g + 7168 + tid * 16);
            *reinterpret_cast<float4*>(lds + LDS_S1 + 7168 + tid * 16) = v;
        } else if (tid >= 64 && tid < 112) {
            const int u = tid - 64;
            float4 v = *reinterpret_cast<const float4*>(s2g + 7168 + u * 16);
            *reinterpret_cast<float4*>(lds + LDS_S2 + 7168 + u * 16) = v;
        } else if (tid >= 128 && tid < 160) {
            const int u = tid - 128;
            float4 v = *reinterpret_cast<const float4*>(bxg + u * 16);
            *reinterpret_cast<float4*>(lds + LDS_BX + u * 16) = v;
        }
        __syncthreads();   // drains vmcnt (DMA) + lgkmcnt (ds_write)

        // ---- compute: one row per thread, 64 rows ----
        if (tid < TILE) {
            const float*  s1r = (const float*)(lds + LDS_S1) + tid * 31;
            const float*  s2r = (const float*)(lds + LDS_S2) + tid * 31;
            const float4* dpr = (const float4*)(lds + LDS_DP) + tid * 14;
            const float2  b2  = reinterpret_cast<const float2*>(lds + LDS_BX)[tid];

            float s1v[31], s2v[30];
            #pragma unroll
            for (int i = 0; i < 31; ++i) s1v[i] = s1r[i];
            #pragma unroll
            for (int i = 0; i < 30; ++i) s2v[i] = s2r[i];

            float sum = b2.x * (s1v[1] - s1v[0]) + b2.y * (s2v[1] - s2v[0]);
            #pragma unroll
            for (int q = 0; q < 14; ++q) {
                const float4 v = dpr[q];
                const int i = 2 * q;
                sum += v.x * (s1v[i + 2] - s1v[i + 1]) + v.y * (s2v[i + 2] - s2v[i + 1]);
                sum += v.z * (s1v[i + 3] - s1v[i + 2]) + v.w * (s2v[i + 3] - s2v[i + 2]);
            }
            const float liab = fmaxf(s1v[30] - 100.0f, 0.0f);
            acc += (double)(w + fmaxf(liab - sum - w, 0.0f) * 2.0f);
        }
        __syncthreads();   // protect LDS before next tile's staging
    }

    // deterministic block reduction (double)
    sm[tid] = acc;
    __syncthreads();
    #pragma unroll
    for (int s = NTHREADS / 2; s > 0; s >>= 1) {
        if (tid < s) sm[tid] += sm[tid + s];
        __syncthreads();
    }
    if (tid == 0) partial[blockIdx.x] = sm[0];
}

__global__ __launch_bounds__(NTHREADS) void loss_final_kernel(
    const double* __restrict__ partial, float* __restrict__ out)
{
    double acc = 0.0;
    for (int i = threadIdx.x; i < NBLOCKS; i += NTHREADS) acc += partial[i];
    __shared__ double sm[NTHREADS];
    sm[threadIdx.x] = acc;
    __syncthreads();
    #pragma unroll
    for (int s = NTHREADS / 2; s > 0; s >>= 1) {
        if (threadIdx.x < s) sm[threadIdx.x] += sm[threadIdx.x + s];
        __syncthreads();
    }
    if (threadIdx.x == 0) out[0] = (float)(sm[0] / (double)NROWS);
}

extern "C" void kernel_launch(void* const* d_in, const int* in_sizes, int n_in,
                              void* d_out, int out_size, void* d_ws, size_t ws_size,
                              hipStream_t stream)
{
    const float* dp = (const float*)d_in[0];   // delta_pred [B,56]
    const float* bx = (const float*)d_in[1];   // batch_x    [B,2]
    const float* S1 = (const float*)d_in[2];   // S1         [B,31]
    const float* S2 = (const float*)d_in[3];   // S2         [B,31]
    const float* w  = (const float*)d_in[4];   // scalar

    double* partial = (double*)d_ws;           // NBLOCKS doubles (16 KiB)
    float* out = (float*)d_out;

    loss_staged_kernel<<<NBLOCKS, NTHREADS, 0, stream>>>(dp, bx, S1, S2, w, partial);
    loss_final_kernel<<<1, NTHREADS, 0, stream>>>(partial, out);
}

// Round 3
// 93.365 us; speedup vs baseline: 3.2850x; 1.0316x over previous
//
#include <hip/hip_runtime.h>

// Problem: N=30, K=100, ALPHA=0.5, B=1048576
#define NROWS    1048576
#define TILE     64                         // rows per tile
#define NBLOCKS  2048
#define NTHREADS 256
#define TILES_PER_BLOCK 8                   // 16384 tiles / 2048 blocks

// Per-tile global byte sizes (contiguous rows)
#define DP_TILE_B (TILE * 224)              // 14336 = 14 x 1KB
#define S_TILE_B  (TILE * 124)              // 7936  = 7 x 1KB + 3 x 256B
#define BX_TILE_B (TILE * 8)                // 512   = 2 x 256B

// LDS layout inside one buffer (no padding needed; all 16B-aligned)
#define LDS_DP 0
#define LDS_S1 14336
#define LDS_S2 22272
#define LDS_BX 30208
#define BUF_B  30720                        // 30 KB per buffer, x2 buffers

// Async global->LDS DMA. LDS dest = wave-uniform base (+ lane*width implicit).
#define GLDS16(g, l) __builtin_amdgcn_global_load_lds(                         \
    (const __attribute__((address_space(1))) void*)(g),                        \
    (__attribute__((address_space(3))) void*)(l), 16, 0, 0)
#define GLDS4(g, l) __builtin_amdgcn_global_load_lds(                          \
    (const __attribute__((address_space(1))) void*)(g),                        \
    (__attribute__((address_space(3))) void*)(l), 4, 0, 0)

// Each wave issues EXACTLY 9 DMA instructions (uniform vmcnt bookkeeping).
__device__ __forceinline__ void stage_tile(unsigned char* buf,
    const char* dpg, const char* s1g, const char* s2g, const char* bxg,
    int wv, int lane)
{
    if (wv == 0) {
        #pragma unroll
        for (int c = 0; c < 9; ++c)
            GLDS16(dpg + c * 1024 + lane * 16, buf + LDS_DP + c * 1024);
    } else if (wv == 1) {
        #pragma unroll
        for (int c = 9; c < 14; ++c)
            GLDS16(dpg + c * 1024 + lane * 16, buf + LDS_DP + c * 1024);
        #pragma unroll
        for (int c = 0; c < 4; ++c)
            GLDS16(s1g + c * 1024 + lane * 16, buf + LDS_S1 + c * 1024);
    } else if (wv == 2) {
        #pragma unroll
        for (int c = 4; c < 7; ++c)
            GLDS16(s1g + c * 1024 + lane * 16, buf + LDS_S1 + c * 1024);
        #pragma unroll
        for (int k = 0; k < 3; ++k)
            GLDS4(s1g + 7168 + k * 256 + lane * 4, buf + LDS_S1 + 7168 + k * 256);
        #pragma unroll
        for (int c = 0; c < 3; ++c)
            GLDS16(s2g + c * 1024 + lane * 16, buf + LDS_S2 + c * 1024);
    } else {
        #pragma unroll
        for (int c = 3; c < 7; ++c)
            GLDS16(s2g + c * 1024 + lane * 16, buf + LDS_S2 + c * 1024);
        #pragma unroll
        for (int k = 0; k < 3; ++k)
            GLDS4(s2g + 7168 + k * 256 + lane * 4, buf + LDS_S2 + 7168 + k * 256);
        #pragma unroll
        for (int k = 0; k < 2; ++k)
            GLDS4(bxg + k * 256 + lane * 4, buf + LDS_BX + k * 256);
    }
}

// All 256 threads compute: 4 lanes per row, 7 pairs each, shuffle-combine.
__device__ __forceinline__ void compute_tile(const unsigned char* buf,
    int row, int seg, float w, double& acc)
{
    const float*  s1row = (const float*)(buf + LDS_S1 + row * 124);
    const float*  s2row = (const float*)(buf + LDS_S2 + row * 124);
    const float2* dprow = (const float2*)(buf + LDS_DP + row * 224);
    const float2  b2    = *(const float2*)(buf + LDS_BX + row * 8);

    const int sb = 7 * seg;                 // this seg's S base index
    float s1v[9], s2v[9];
    #pragma unroll
    for (int i = 0; i < 9; ++i) { s1v[i] = s1row[sb + i]; s2v[i] = s2row[sb + i]; }

    // pairs p = 7*seg + u : dS[p] = S[p+2]-S[p+1] = v[u+2]-v[u+1]
    float sum = 0.0f;
    #pragma unroll
    for (int u = 0; u < 7; ++u) {
        const float2 d = dprow[sb + u];     // (d1[p], d2[p])
        sum += d.x * (s1v[u + 2] - s1v[u + 1]) + d.y * (s2v[u + 2] - s2v[u + 1]);
    }
    const float t0 = b2.x * (s1v[1] - s1v[0]) + b2.y * (s2v[1] - s2v[0]);
    sum += (seg == 0) ? t0 : 0.0f;          // boundary term once per row

    sum += __shfl_xor(sum, 1);              // combine 4 segments
    sum += __shfl_xor(sum, 2);

    const float liab = fmaxf(s1row[30] - 100.0f, 0.0f);
    const float loss = w + fmaxf(liab - sum - w, 0.0f) * 2.0f;   // /(1-ALPHA)
    if (seg == 0) acc += (double)loss;
}

__global__ __launch_bounds__(NTHREADS) void loss_pipe_kernel(
    const float* __restrict__ dp, const float* __restrict__ bx,
    const float* __restrict__ S1, const float* __restrict__ S2,
    const float* __restrict__ wp, double* __restrict__ partial)
{
    __shared__ __align__(16) unsigned char lds[2 * BUF_B];
    __shared__ double sm[NTHREADS];

    const int tid  = threadIdx.x;
    const int lane = tid & 63;
    const int wv   = tid >> 6;
    const int row  = tid >> 2;              // 0..63
    const int seg  = tid & 3;               // 0..3
    const float w  = *wp;

    const long tile0 = (long)blockIdx.x * TILES_PER_BLOCK;
    double acc = 0.0;

    // prologue: stage tile 0 into buf0
    stage_tile(lds,
               (const char*)dp + tile0 * DP_TILE_B,
               (const char*)S1 + tile0 * S_TILE_B,
               (const char*)S2 + tile0 * S_TILE_B,
               (const char*)bx + tile0 * BX_TILE_B, wv, lane);

    for (int t = 0; t < TILES_PER_BLOCK - 1; ++t) {
        const long nt = tile0 + t + 1;
        stage_tile(lds + ((t + 1) & 1) * BUF_B,     // prefetch next tile
                   (const char*)dp + nt * DP_TILE_B,
                   (const char*)S1 + nt * S_TILE_B,
                   (const char*)S2 + nt * S_TILE_B,
                   (const char*)bx + nt * BX_TILE_B, wv, lane);
        // counted wait: current tile's 9 DMAs done, prefetch's 9 stay in flight
        asm volatile("s_waitcnt vmcnt(9)" ::: "memory");
        __builtin_amdgcn_s_barrier();
        compute_tile(lds + (t & 1) * BUF_B, row, seg, w, acc);
        __builtin_amdgcn_s_barrier();       // all done reading before overwrite
    }
    // epilogue: last tile
    asm volatile("s_waitcnt vmcnt(0)" ::: "memory");
    __builtin_amdgcn_s_barrier();
    compute_tile(lds + ((TILES_PER_BLOCK - 1) & 1) * BUF_B, row, seg, w, acc);

    // deterministic block reduction (double)
    sm[tid] = acc;
    __syncthreads();
    #pragma unroll
    for (int s = NTHREADS / 2; s > 0; s >>= 1) {
        if (tid < s) sm[tid] += sm[tid + s];
        __syncthreads();
    }
    if (tid == 0) partial[blockIdx.x] = sm[0];
}

__global__ __launch_bounds__(NTHREADS) void loss_final_kernel(
    const double* __restrict__ partial, float* __restrict__ out)
{
    double acc = 0.0;
    for (int i = threadIdx.x; i < NBLOCKS; i += NTHREADS) acc += partial[i];
    __shared__ double sm[NTHREADS];
    sm[threadIdx.x] = acc;
    __syncthreads();
    #pragma unroll
    for (int s = NTHREADS / 2; s > 0; s >>= 1) {
        if (threadIdx.x < s) sm[threadIdx.x] += sm[threadIdx.x + s];
        __syncthreads();
    }
    if (threadIdx.x == 0) out[0] = (float)(sm[0] / (double)NROWS);
}

extern "C" void kernel_launch(void* const* d_in, const int* in_sizes, int n_in,
                              void* d_out, int out_size, void* d_ws, size_t ws_size,
                              hipStream_t stream)
{
    const float* dp = (const float*)d_in[0];   // delta_pred [B,56]
    const float* bx = (const float*)d_in[1];   // batch_x    [B,2]
    const float* S1 = (const float*)d_in[2];   // S1         [B,31]
    const float* S2 = (const float*)d_in[3];   // S2         [B,31]
    const float* w  = (const float*)d_in[4];   // scalar

    double* partial = (double*)d_ws;           // NBLOCKS doubles (16 KiB)
    float* out = (float*)d_out;

    loss_pipe_kernel<<<NBLOCKS, NTHREADS, 0, stream>>>(dp, bx, S1, S2, w, partial);
    loss_final_kernel<<<1, NTHREADS, 0, stream>>>(partial, out);
}